// Round 15
// baseline (32.637 us; speedup 1.0000x reference)
//
#include <hip/hip_runtime.h>
#include <math.h>

// Problem constants (fixed by setup_inputs)
#define BB 2
#define TT 5
#define NPTS 4096
#define NBT (BB * TT)
#define NELEM (BB * TT * 64 * 2048)   // 1,310,720

// Chamfer: 2 dir x 10 bt x 64 qc = 1280 blocks (bids 0..1279), 64 queries each.
// Each wave: all 64 queries vs its own 1024-point quarter.
#define CH_BLOCKS 1280
#define NQC 64
#define EW_BLOCKS 640                 // bids 1280..1919

// ws layout (floats):
//   [0..1280)      chamfer partials, slot = dir*640 + bt*64 + qc
//   [1280..1920)   ew srv partials
//   [1920..2560)   ew smk partials
#define EW1 1280
#define EW2 1920

typedef _Float16 h8 __attribute__((ext_vector_type(8)));
typedef __fp16 fp16x2 __attribute__((ext_vector_type(2)));
typedef float f32x16 __attribute__((ext_vector_type(16)));
typedef float f32x4 __attribute__((ext_vector_type(4)));

__device__ inline unsigned pk2(float a, float b) {
    union { fp16x2 h; unsigned u; } c;
    c.h = __builtin_amdgcn_cvt_pkrtz(a, b);   // v_cvt_pkrtz_f16_f32, 1 instr
    return c.u;
}

__global__ __launch_bounds__(256) void main_kernel(
        const float4* __restrict__ rv4,
        const float4* __restrict__ lg4,
        const float4* __restrict__ tg4,
        const float* __restrict__ OP,
        const float* __restrict__ TP,
        float* __restrict__ ws) {
    __shared__ __align__(16) uint2 pts[4096];   // (x,y)f16,(z,n)f16 per point, 32 KB
    __shared__ float nqlds[64];
    __shared__ float qmin[4][64];
    int bid = blockIdx.x;
    int tid = threadIdx.x;
    int lane = tid & 63;
    int wave = tid >> 6;

    if (bid >= CH_BLOCKS) {
        // ---------------- elementwise: L1 range + BCE mask ----------------
        int eb = bid - CH_BLOCKS;
        float srv = 0.0f, smk = 0.0f;
        int base = (eb * 256 + tid) * 2;
#pragma unroll
        for (int u = 0; u < 2; ++u) {
            int i = base + u;
            float4 o4 = rv4[i];
            float4 x4 = lg4[i];
            float4 t4 = tg4[i];
            const float* op = &o4.x;
            const float* xp = &x4.x;
            const float* tp = &t4.x;
#pragma unroll
            for (int j = 0; j < 4; ++j) {
                float tv = tp[j];
                float ov = (tv == -1.0f) ? -1.0f : op[j];
                srv += fabsf(ov - tv);
                float tm = (tv > 0.0f) ? 1.0f : 0.0f;
                float xv = xp[j];
                smk += fmaxf(xv, 0.0f) - xv * tm + __logf(1.0f + __expf(-fabsf(xv)));
            }
        }
#pragma unroll
        for (int off = 32; off > 0; off >>= 1) {
            srv += __shfl_down(srv, off);
            smk += __shfl_down(smk, off);
        }
        __shared__ float s1[4], s2[4];
        if (lane == 0) { s1[wave] = srv; s2[wave] = smk; }
        __syncthreads();
        if (tid == 0) {
            ws[EW1 + eb] = s1[0] + s1[1] + s1[2] + s1[3];
            ws[EW2 + eb] = s2[0] + s2[1] + s2[2] + s2[3];
        }
        return;
    }

    // ------------- chamfer via MFMA: 64 queries x 4096 points per block -------------
    int dir = bid / (NBT * NQC);
    int rem = bid % (NBT * NQC);
    int bt = rem / NQC;
    int qc = rem % NQC;
    const float* P = dir ? TP : OP;      // queries
    const float* Q = dir ? OP : TP;      // references
    const float* Pb = P + (size_t)bt * NPTS * 3;
    const float* Qb = Q + (size_t)bt * NPTS * 3;

    int qrow = lane & 31;

    // Two A fragments: low queries (0..31) and high (32..63).
    // A row = lane&31, k = (lane>>5)*8 + slot. Data lives in k=0..3 of lanes<32;
    // all other k slots are zero on the A side (lanes>=32) or the B side (u[2..3]).
    int qbase = qc * 64 + qrow;
    const float* pL = Pb + (size_t)qbase * 3;
    const float* pH = pL + 32 * 3;
    float lx = pL[0], ly = pL[1], lz = pL[2];
    float hx = pH[0], hy = pH[1], hz = pH[2];
    nqlds[qrow] = fmaf(lx, lx, fmaf(ly, ly, lz * lz));        // dup writes benign
    nqlds[32 + qrow] = fmaf(hx, hx, fmaf(hy, hy, hz * hz));
    union { unsigned u[4]; h8 h; } uaL, uaH;
    uaL.u[0] = uaL.u[1] = uaL.u[2] = uaL.u[3] = 0u;
    uaH.u[0] = uaH.u[1] = uaH.u[2] = uaH.u[3] = 0u;
    if (lane < 32) {
        uaL.u[0] = pk2(-2.0f * lx, -2.0f * ly);
        uaL.u[1] = pk2(-2.0f * lz, 1.0f);
        uaH.u[0] = pk2(-2.0f * hx, -2.0f * hy);
        uaH.u[1] = pk2(-2.0f * hz, 1.0f);
    }
    h8 aL = uaL.h, aH = uaH.h;

    // Stage ALL 4096 points as f16 (x,y | z,n); 16 points per thread.
#pragma unroll
    for (int t = 0; t < 4; ++t) {
        int pt0 = t * 1024 + tid * 4;
        const f32x4* src = (const f32x4*)(Qb + (size_t)pt0 * 3);
        f32x4 c0 = src[0], c1 = src[1], c2 = src[2];
        float x0 = c0[0], y0 = c0[1], z0 = c0[2];
        float x1 = c0[3], y1 = c1[0], z1 = c1[1];
        float x2 = c1[2], y2 = c1[3], z2 = c2[0];
        float x3 = c2[1], y3 = c2[2], z3 = c2[3];
        float n0 = fmaf(x0, x0, fmaf(y0, y0, z0 * z0));
        float n1 = fmaf(x1, x1, fmaf(y1, y1, z1 * z1));
        float n2 = fmaf(x2, x2, fmaf(y2, y2, z2 * z2));
        float n3 = fmaf(x3, x3, fmaf(y3, y3, z3 * z3));
        uint4* dst = (uint4*)&pts[t * 1024 + tid * 4];
        dst[0] = make_uint4(pk2(x0, y0), pk2(z0, n0), pk2(x1, y1), pk2(z1, n1));
        dst[1] = make_uint4(pk2(x2, y2), pk2(z2, n2), pk2(x3, y3), pk2(z3, n3));
    }
    __syncthreads();

    const f32x16 zc = {0.0f, 0.0f, 0.0f, 0.0f, 0.0f, 0.0f, 0.0f, 0.0f,
                       0.0f, 0.0f, 0.0f, 0.0f, 0.0f, 0.0f, 0.0f, 0.0f};
    float vmL[16], vmH[16];
#pragma unroll
    for (int r = 0; r < 16; ++r) { vmL[r] = INFINITY; vmH[r] = INFINITY; }

    // Each wave: its own 1024-point quarter; every ds_read feeds 2 MFMAs.
    const uint2* pb = pts + wave * 1024;
#pragma unroll 4
    for (int g = 0; g < 16; ++g) {       // 16 groups x 64 points
        uint2 b0 = pb[g * 64 + qrow];            // lanes>=32 broadcast same addr
        uint2 b1 = pb[g * 64 + 32 + qrow];
        union { unsigned u[4]; h8 h; } ub0, ub1;
        ub0.u[0] = b0.x; ub0.u[1] = b0.y; ub0.u[2] = 0u; ub0.u[3] = 0u;
        ub1.u[0] = b1.x; ub1.u[1] = b1.y; ub1.u[2] = 0u; ub1.u[3] = 0u;
        f32x16 dL0 = __builtin_amdgcn_mfma_f32_32x32x16_f16(aL, ub0.h, zc, 0, 0, 0);
        f32x16 dL1 = __builtin_amdgcn_mfma_f32_32x32x16_f16(aL, ub1.h, zc, 0, 0, 0);
        f32x16 dH0 = __builtin_amdgcn_mfma_f32_32x32x16_f16(aH, ub0.h, zc, 0, 0, 0);
        f32x16 dH1 = __builtin_amdgcn_mfma_f32_32x32x16_f16(aH, ub1.h, zc, 0, 0, 0);
#pragma unroll
        for (int r = 0; r < 16; ++r) {
            float a = dL0[r], c = dL1[r];
            asm("v_min3_f32 %0, %0, %1, %2" : "+v"(vmL[r]) : "v"(a), "v"(c));
        }
#pragma unroll
        for (int r = 0; r < 16; ++r) {
            float a = dH0[r], c = dH1[r];
            asm("v_min3_f32 %0, %0, %1, %2" : "+v"(vmH[r]) : "v"(a), "v"(c));
        }
    }

    // column-min across each 32-lane half (cols = points)
#pragma unroll
    for (int r = 0; r < 16; ++r) {
        float mL = vmL[r], mH = vmH[r];
        mL = fminf(mL, __shfl_xor(mL, 1));
        mH = fminf(mH, __shfl_xor(mH, 1));
        mL = fminf(mL, __shfl_xor(mL, 2));
        mH = fminf(mH, __shfl_xor(mH, 2));
        mL = fminf(mL, __shfl_xor(mL, 4));
        mH = fminf(mH, __shfl_xor(mH, 4));
        mL = fminf(mL, __shfl_xor(mL, 8));
        mH = fminf(mH, __shfl_xor(mH, 8));
        mL = fminf(mL, __shfl_xor(mL, 16));
        mH = fminf(mH, __shfl_xor(mH, 16));
        vmL[r] = mL; vmH[r] = mH;
    }
    if ((lane & 31) == 0) {
        int h4 = (lane >> 5) * 4;
#pragma unroll
        for (int r = 0; r < 16; ++r) {
            int row = (r & 3) + 8 * (r >> 2) + h4;
            qmin[wave][row] = vmL[r];
            qmin[wave][32 + row] = vmH[r];
        }
    }
    __syncthreads();

    // combine the 4 point quarters, add ||p||^2, sum 64 queries -> one partial
    if (wave == 0) {
        float m = fminf(fminf(qmin[0][lane], qmin[1][lane]),
                        fminf(qmin[2][lane], qmin[3][lane])) + nqlds[lane];
#pragma unroll
        for (int off = 32; off > 0; off >>= 1) m += __shfl_down(m, off);
        if (lane == 0) ws[bid] = m;
    }
}

__global__ void finalize_kernel(const float* __restrict__ ws, float* __restrict__ out) {
    __shared__ float grp[20];
    __shared__ float ra[4], rb[4];
    int tid = threadIdx.x;
    int lane = tid & 63;
    int wave = tid >> 6;

    // chamfer partials: 20 groups (dir*10+bt) of exactly 64
    for (int g = wave; g < 20; g += 4) {
        float s = ws[g * 64 + lane];
#pragma unroll
        for (int off = 32; off > 0; off >>= 1) s += __shfl_down(s, off);
        if (lane == 0) grp[g] = s;
    }

    // ew partials: 640 each
    float sa = 0.0f, sb = 0.0f;
    for (int i = tid; i < EW_BLOCKS; i += 256) {
        sa += ws[EW1 + i];
        sb += ws[EW2 + i];
    }
#pragma unroll
    for (int off = 32; off > 0; off >>= 1) {
        sa += __shfl_down(sa, off);
        sb += __shfl_down(sb, off);
    }
    if (lane == 0) { ra[wave] = sa; rb[wave] = sb; }
    __syncthreads();

    if (tid == 0) {
        const float inv_e = 1.0f / (float)NELEM;
        float loss_rv = (ra[0] + ra[1] + ra[2] + ra[3]) * inv_e;
        float loss_mask = (rb[0] + rb[1] + rb[2] + rb[3]) * inv_e;
        float cd_sum = 0.0f;
        for (int bt = 0; bt < NBT; ++bt) {
            float cd = (grp[bt] + grp[NBT + bt]) * (1.0f / NPTS);
            int b = bt / TT;
            int t = bt % TT;
            out[1 + t * BB + b] = cd;   // cd_tensor is [T,B]
            cd_sum += cd;
        }
        float loss_cd = cd_sum / (float)NBT;
        out[0] = loss_cd + loss_rv + loss_mask;  // weights all 1.0
        out[11] = loss_cd;
        out[12] = loss_rv;
        out[13] = loss_mask;
    }
}

extern "C" void kernel_launch(void* const* d_in, const int* in_sizes, int n_in,
                              void* d_out, int out_size, void* d_ws, size_t ws_size,
                              hipStream_t stream) {
    const float* output_rv = (const float*)d_in[0];
    const float* mask_logits = (const float*)d_in[1];
    const float* output_points = (const float*)d_in[2];
    const float* target_points = (const float*)d_in[3];
    const float* target_rv = (const float*)d_in[4];
    float* out = (float*)d_out;
    float* ws = (float*)d_ws;

    main_kernel<<<CH_BLOCKS + EW_BLOCKS, 256, 0, stream>>>(
        (const float4*)output_rv, (const float4*)mask_logits,
        (const float4*)target_rv, output_points, target_points, ws);

    finalize_kernel<<<1, 256, 0, stream>>>(ws, out);
}